// Round 2
// baseline (1180.415 us; speedup 1.0000x reference)
//
#include <hip/hip_runtime.h>
#include <math.h>

#define TLEN 2048
#define TP 256

// ---------------- helpers ----------------
__device__ __forceinline__ double block_reduce_sum_d(double v, double* sm) {
#pragma unroll
  for (int off = 32; off > 0; off >>= 1) v += __shfl_down(v, off, 64);
  int lane = threadIdx.x & 63, wid = threadIdx.x >> 6;
  __syncthreads();
  if (lane == 0) sm[wid] = v;
  __syncthreads();
  double r = sm[0] + sm[1] + sm[2] + sm[3];
  __syncthreads();
  return r;
}

// ---------------- repack tconv1 weights: w[o][i][k] -> wT[k][i][o] (f32, exact) ------
__global__ void k_repack_w(const float* __restrict__ w, float* __restrict__ wT) {
  int idx = blockIdx.x * 256 + threadIdx.x;
  if (idx >= 64 * 64 * 15) return;
  int o = idx & 63, i = (idx >> 6) & 63, k = idx >> 12;
  wT[idx] = w[(o * 64 + i) * 15 + k];
}

// ---------------- pooled curvature/tangent streams -> (tp, b, c) ----------------
template <typename T>
__global__ __launch_bounds__(256) void k_pool_ct(const float* __restrict__ xb,
                                                 T* __restrict__ curvp,
                                                 T* __restrict__ tangp) {
  int row = blockIdx.x;  // b*64+c
  int b = row >> 6, c = row & 63;
  int tid = threadIdx.x;
  const float* s1 = xb + ((size_t)((b * 3 + 1) * 64 + c)) * TLEN + tid * 8;
  const float* s2 = xb + ((size_t)((b * 3 + 2) * 64 + c)) * TLEN + tid * 8;
  double p1 = 0.0, p2 = 0.0;
#pragma unroll
  for (int j = 0; j < 8; ++j) { p1 += (double)s1[j]; p2 += (double)s2[j]; }
  curvp[(size_t)tid * 2048 + row] = (T)(p1 * 0.125);
  tangp[(size_t)tid * 2048 + row] = (T)(p2 * 0.125);
}

// ---------------- enc (gaussian, f64) fused with conv1: 128 o x 128 t tile ----------
template <typename T>
__global__ __launch_bounds__(256, 2) void k_enc_conv1(const float* __restrict__ xb,
                                                      const float* __restrict__ w,
                                                      const float* __restrict__ mu,
                                                      const float* __restrict__ sigma,
                                                      T* __restrict__ h1) {
  __shared__ float As[128][33];     // weights (f32 exact)
  __shared__ double Bs[32][132];    // enc values (f64)
  __shared__ float rxb[8][128];     // raw input (f32 exact)
  __shared__ double smu[4], sinv[4];
  int b = blockIdx.x, t0 = blockIdx.y * 128, tid = threadIdx.x;
  if (tid < 4) {
    smu[tid] = (double)mu[tid];
    double s = (double)sigma[tid];
    sinv[tid] = 1.0 / (2.0 * s * s + 1e-6);
  }
  double acc[8][8] = {};
  int to = (tid >> 4) * 8, tt = (tid & 15) * 8;
  for (int kc = 0; kc < 24; ++kc) {
    int i0 = kc * 32;
    __syncthreads();
    for (int base = tid * 4; base < 4096; base += 1024) {
      int o = base >> 5, ii = base & 31;
      float4 v4 = *(const float4*)(w + (size_t)o * 768 + i0 + ii);
      As[o][ii] = v4.x; As[o][ii + 1] = v4.y; As[o][ii + 2] = v4.z; As[o][ii + 3] = v4.w;
    }
    {
      int r = tid >> 5, col = (tid & 31) * 4;
      int f = i0 >> 8, c = ((i0 >> 2) & 63) + r;
      float4 v4 = *(const float4*)(xb + ((size_t)((b * 3 + f) * 64 + c)) * TLEN + t0 + col);
      rxb[r][col] = v4.x; rxb[r][col + 1] = v4.y; rxb[r][col + 2] = v4.z; rxb[r][col + 3] = v4.w;
    }
    __syncthreads();
    {
      int il = tid >> 3;             // 0..31 local channel
      int g = il & 3, cl = il >> 2;
      double m = smu[g], inv = sinv[g];
      int ts = (tid & 7) * 16;
#pragma unroll
      for (int j = 0; j < 16; ++j) {
        double x = (double)rxb[cl][ts + j];
        double d = x - m;
        Bs[il][ts + j] = exp(-d * d * inv);
      }
    }
    __syncthreads();
#pragma unroll
    for (int kk = 0; kk < 32; ++kk) {
      double a[8], bb[8];
#pragma unroll
      for (int q = 0; q < 8; ++q) a[q] = (double)As[to + q][kk];
#pragma unroll
      for (int j = 0; j < 8; ++j) bb[j] = Bs[kk][tt + j];
#pragma unroll
      for (int q = 0; q < 8; ++q)
#pragma unroll
        for (int j = 0; j < 8; ++j) acc[q][j] += a[q] * bb[j];
    }
  }
#pragma unroll
  for (int q = 0; q < 8; ++q) {
    T* op = h1 + ((size_t)(b * 128 + to + q)) * TLEN + t0 + tt;
#pragma unroll
    for (int j = 0; j < 8; ++j) op[j] = (T)acc[q][j];
  }
}

// ---------------- generic 1x1 conv: out[64][T] = W[64][K] * in[K][T], f64 math ------
template <int K, typename T>
__global__ __launch_bounds__(256) void k_conv1x1(const T* __restrict__ in,
                                                 const float* __restrict__ w,
                                                 T* __restrict__ out) {
  __shared__ float As[64][33];
  __shared__ double Bs[32][132];
  int b = blockIdx.x, t0 = blockIdx.y * 128, tid = threadIdx.x;
  double acc[4][8] = {};
  int to = (tid >> 4) * 4, tt = (tid & 15) * 8;
  for (int kc = 0; kc < K / 32; ++kc) {
    __syncthreads();
    for (int base = tid * 4; base < 2048; base += 1024) {
      int o = base >> 5, ii = base & 31;
      float4 v4 = *(const float4*)(w + (size_t)o * K + kc * 32 + ii);
      As[o][ii] = v4.x; As[o][ii + 1] = v4.y; As[o][ii + 2] = v4.z; As[o][ii + 3] = v4.w;
    }
    {
      int r = tid >> 3, cb = (tid & 7) * 16;
      const T* gp = in + ((size_t)(b * K + kc * 32 + r)) * TLEN + t0 + cb;
#pragma unroll
      for (int j = 0; j < 16; ++j) Bs[r][cb + j] = (double)gp[j];
    }
    __syncthreads();
#pragma unroll
    for (int kk = 0; kk < 32; ++kk) {
      double a0 = (double)As[to][kk], a1 = (double)As[to + 1][kk];
      double a2 = (double)As[to + 2][kk], a3 = (double)As[to + 3][kk];
      double bb[8];
#pragma unroll
      for (int j = 0; j < 8; ++j) bb[j] = Bs[kk][tt + j];
#pragma unroll
      for (int j = 0; j < 8; ++j) {
        acc[0][j] += a0 * bb[j];
        acc[1][j] += a1 * bb[j];
        acc[2][j] += a2 * bb[j];
        acc[3][j] += a3 * bb[j];
      }
    }
  }
#pragma unroll
  for (int q = 0; q < 4; ++q) {
    T* op = out + ((size_t)(b * 64 + to + q)) * TLEN + t0 + tt;
#pragma unroll
    for (int j = 0; j < 8; ++j) op[j] = (T)acc[q][j];
  }
}

// ---------------- temporal conv k=15 pad=7, f64 math, 64 o x 64 t tile --------------
template <typename T>
__global__ __launch_bounds__(256) void k_tconv1(const T* __restrict__ h2,
                                                const float* __restrict__ wT,
                                                T* __restrict__ h3) {
  __shared__ double In[64][80];   // t0-8 .. t0+71
  __shared__ float Ws[64][68];    // [i][o] for one k (f32 exact)
  int b = blockIdx.x, t0 = blockIdx.y * 64, tid = threadIdx.x;
  for (int idx = tid; idx < 64 * 80; idx += 256) {
    int i = idx / 80, tt = idx - i * 80;
    int tg = t0 - 8 + tt;
    double v = 0.0;
    if (tg >= 0 && tg < TLEN) v = (double)h2[((size_t)(b * 64 + i)) * TLEN + tg];
    In[i][tt] = v;
  }
  double acc[4][4] = {};
  int to = (tid >> 4) * 4, tt2 = (tid & 15) * 4;
  for (int k = 0; k < 15; ++k) {
    __syncthreads();
    {
      int i = tid >> 2, seg = (tid & 3) * 16;
      const float* wp = wT + (size_t)(k * 64 + i) * 64 + seg;
      float4 v0 = *(const float4*)wp;
      float4 v1 = *(const float4*)(wp + 4);
      float4 v2 = *(const float4*)(wp + 8);
      float4 v3 = *(const float4*)(wp + 12);
      *(float4*)&Ws[i][seg] = v0;
      *(float4*)&Ws[i][seg + 4] = v1;
      *(float4*)&Ws[i][seg + 8] = v2;
      *(float4*)&Ws[i][seg + 12] = v3;
    }
    __syncthreads();
#pragma unroll 4
    for (int i = 0; i < 64; ++i) {
      float4 av4 = *(const float4*)&Ws[i][to];
      double av0 = (double)av4.x, av1 = (double)av4.y, av2 = (double)av4.z, av3 = (double)av4.w;
      double bv[4];
#pragma unroll
      for (int j = 0; j < 4; ++j) bv[j] = In[i][tt2 + k + 1 + j];
#pragma unroll
      for (int j = 0; j < 4; ++j) {
        acc[0][j] += av0 * bv[j];
        acc[1][j] += av1 * bv[j];
        acc[2][j] += av2 * bv[j];
        acc[3][j] += av3 * bv[j];
      }
    }
  }
#pragma unroll
  for (int q = 0; q < 4; ++q) {
    T* op = h3 + ((size_t)(b * 64 + to + q)) * TLEN + t0 + tt2;
#pragma unroll
    for (int j = 0; j < 4; ++j) op[j] = (T)acc[q][j];
  }
}

// ---------------- instance norm + relu, in place, f64 stats -------------------------
template <typename T>
__global__ __launch_bounds__(256) void k_instnorm_relu(T* __restrict__ h,
                                                       const float* __restrict__ gw,
                                                       const float* __restrict__ gb,
                                                       int chmask) {
  __shared__ double sm[4];
  int row = blockIdx.x, tid = threadIdx.x;
  int ch = row & chmask;
  T* base = h + (size_t)row * TLEN + tid * 8;
  double v[8];
#pragma unroll
  for (int j = 0; j < 8; ++j) v[j] = (double)base[j];
  double s = 0.0;
#pragma unroll
  for (int j = 0; j < 8; ++j) s += v[j];
  double mean = block_reduce_sum_d(s, sm) * (1.0 / 2048.0);
  double sq = 0.0;
#pragma unroll
  for (int j = 0; j < 8; ++j) { double d = v[j] - mean; sq += d * d; }
  double var = block_reduce_sum_d(sq, sm) * (1.0 / 2048.0);
  double scale = (double)gw[ch] / sqrt(var + 1e-5);
  double shift = (double)gb[ch] - mean * scale;
#pragma unroll
  for (int j = 0; j < 8; ++j) base[j] = (T)fmax(v[j] * scale + shift, 0.0);
}

// ---------------- IN4 + relu + avgpool8 -> cbuf[tp][b][c], f64 ----------------------
template <typename T>
__global__ __launch_bounds__(256) void k_in4_pool(const T* __restrict__ h,
                                                  const float* __restrict__ gw,
                                                  const float* __restrict__ gb,
                                                  T* __restrict__ cbuf) {
  __shared__ double sm[4];
  int row = blockIdx.x, tid = threadIdx.x;
  int ch = row & 63;
  const T* base = h + (size_t)row * TLEN + tid * 8;
  double v[8];
#pragma unroll
  for (int j = 0; j < 8; ++j) v[j] = (double)base[j];
  double s = 0.0;
#pragma unroll
  for (int j = 0; j < 8; ++j) s += v[j];
  double mean = block_reduce_sum_d(s, sm) * (1.0 / 2048.0);
  double sq = 0.0;
#pragma unroll
  for (int j = 0; j < 8; ++j) { double d = v[j] - mean; sq += d * d; }
  double var = block_reduce_sum_d(sq, sm) * (1.0 / 2048.0);
  double scale = (double)gw[ch] / sqrt(var + 1e-5);
  double shift = (double)gb[ch] - mean * scale;
  double p = 0.0;
#pragma unroll
  for (int j = 0; j < 8; ++j) p += fmax(v[j] * scale + shift, 0.0);
  cbuf[(size_t)tid * 2048 + row] = (T)(p * 0.125);
}

// ---------------- GD-LIF scan + softmax attention readout, f64 ---------------------
template <typename T>
__global__ __launch_bounds__(64) void k_scan(const T* __restrict__ cbuf,
                                             const T* __restrict__ curvp,
                                             const T* __restrict__ tangp,
                                             const float* __restrict__ alpha,
                                             const float* __restrict__ gamma,
                                             const float* __restrict__ betal,
                                             double* __restrict__ ofeat) {
  int id = blockIdx.x * 64 + threadIdx.x;  // b*64+c
  double a = (double)alpha[0], g = (double)gamma[0], bl = (double)betal[0];
  double mmax = -1e300, ssum = 0.0;
  for (int tp = 0; tp < TP; ++tp) {
    double v = (double)curvp[(size_t)tp * 2048 + id];
    double nm = fmax(mmax, v);
    ssum = ssum * exp(mmax - nm) + exp(v - nm);
    mmax = nm;
  }
  double invs = 1.0 / ssum;
  double mem = 0.0, acc = 0.0;
  for (int tp = 0; tp < TP; ++tp) {
    double x = (double)cbuf[(size_t)tp * 2048 + id];
    double cu = (double)curvp[(size_t)tp * 2048 + id];
    double ta = (double)tangp[(size_t)tp * 2048 + id];
    double vth = 1.0 + a * ta;
    double beta = 1.0 / (1.0 + exp(g * cu - bl));
    mem = beta * mem + x;
    if (mem - vth > 0.0) {
      acc += exp(cu - mmax) * invs;
      mem -= vth;
    }
  }
  ofeat[id] = acc;
}

// ---------------- final fc: (32,64) @ (4,64)^T + b, f64 -----------------------------
__global__ void k_fc(const double* __restrict__ ofeat, const float* __restrict__ fw,
                     const float* __restrict__ fb, float* __restrict__ out) {
  int tid = threadIdx.x;
  if (tid >= 128) return;
  int b = tid >> 2, j = tid & 3;
  double s = (double)fb[j];
#pragma unroll
  for (int c = 0; c < 64; ++c) s += ofeat[b * 64 + c] * (double)fw[j * 64 + c];
  out[b * 4 + j] = (float)s;
}

// ---------------- host-side templated launcher --------------------------------------
template <typename T>
static void run_all(void* const* d_in, float* out, char* wsb, hipStream_t stream) {
  const float* xb    = (const float*)d_in[0];
  const float* mu    = (const float*)d_in[1];
  const float* sigma = (const float*)d_in[2];
  const float* w1    = (const float*)d_in[3];
  const float* in1w  = (const float*)d_in[4];
  const float* in1b  = (const float*)d_in[5];
  const float* w2    = (const float*)d_in[6];
  const float* in2w  = (const float*)d_in[7];
  const float* in2b  = (const float*)d_in[8];
  const float* wt1   = (const float*)d_in[9];
  const float* in3w  = (const float*)d_in[10];
  const float* in3b  = (const float*)d_in[11];
  const float* w4    = (const float*)d_in[12];
  const float* in4w  = (const float*)d_in[13];
  const float* in4b  = (const float*)d_in[14];
  const float* alpha = (const float*)d_in[15];
  const float* gamma = (const float*)d_in[16];
  const float* betal = (const float*)d_in[17];
  const float* fcw   = (const float*)d_in[18];
  const float* fcb   = (const float*)d_in[19];

  size_t sT = sizeof(T);
  T* h1 = (T*)wsb;                                   // 8,388,608 elems (alias h3)
  T* h2 = (T*)(wsb + (size_t)8388608 * sT);          // 4,194,304 elems (alias h4)
  T* h3 = h1;
  T* h4 = h2;
  float* wT = (float*)(wsb + (size_t)12582912 * sT); // 61,440 f32
  char* p = wsb + (size_t)12582912 * sT + 245760;
  T* curvp = (T*)p;
  T* tangp = (T*)(p + (size_t)524288 * sT);
  T* cbuf  = (T*)(p + (size_t)2 * 524288 * sT);
  double* ofeat = (double*)(p + (size_t)3 * 524288 * sT);

  k_repack_w<<<dim3(240), dim3(256), 0, stream>>>(wt1, wT);
  k_pool_ct<T><<<dim3(2048), dim3(256), 0, stream>>>(xb, curvp, tangp);
  k_enc_conv1<T><<<dim3(32, 16), dim3(256), 0, stream>>>(xb, w1, mu, sigma, h1);
  k_instnorm_relu<T><<<dim3(4096), dim3(256), 0, stream>>>(h1, in1w, in1b, 127);
  k_conv1x1<128, T><<<dim3(32, 16), dim3(256), 0, stream>>>(h1, w2, h2);
  k_instnorm_relu<T><<<dim3(2048), dim3(256), 0, stream>>>(h2, in2w, in2b, 63);
  k_tconv1<T><<<dim3(32, 32), dim3(256), 0, stream>>>(h2, wT, h3);
  k_instnorm_relu<T><<<dim3(2048), dim3(256), 0, stream>>>(h3, in3w, in3b, 63);
  k_conv1x1<64, T><<<dim3(32, 16), dim3(256), 0, stream>>>(h3, w4, h4);
  k_in4_pool<T><<<dim3(2048), dim3(256), 0, stream>>>(h4, in4w, in4b, cbuf);
  k_scan<T><<<dim3(32), dim3(64), 0, stream>>>(cbuf, curvp, tangp, alpha, gamma, betal, ofeat);
  k_fc<<<dim3(1), dim3(128), 0, stream>>>(ofeat, fcw, fcb, out);
}

extern "C" void kernel_launch(void* const* d_in, const int* in_sizes, int n_in,
                              void* d_out, int out_size, void* d_ws, size_t ws_size,
                              hipStream_t stream) {
  // f64-storage footprint: 12,582,912*8 + 245,760 + 3*524,288*8 + 16,384 = 113,508,352 B
  const size_t NEED64 = 113508352ull;
  if (ws_size >= NEED64)
    run_all<double>(d_in, (float*)d_out, (char*)d_ws, stream);
  else
    run_all<float>(d_in, (float*)d_out, (char*)d_ws, stream);
}

// Round 3
// 876.631 us; speedup vs baseline: 1.3465x; 1.3465x over previous
//
#include <hip/hip_runtime.h>
#include <math.h>

#define TLEN 2048
#define TP 256

// ---------------- helpers ----------------
__device__ __forceinline__ double block_reduce_sum_d(double v, double* sm) {
#pragma unroll
  for (int off = 32; off > 0; off >>= 1) v += __shfl_down(v, off, 64);
  int lane = threadIdx.x & 63, wid = threadIdx.x >> 6;
  __syncthreads();
  if (lane == 0) sm[wid] = v;
  __syncthreads();
  double r = sm[0] + sm[1] + sm[2] + sm[3];
  __syncthreads();
  return r;
}

// ---------------- repack tconv1 weights: w[o][i][k] -> wT[k][i][o] (f32, exact) ------
__global__ void k_repack_w(const float* __restrict__ w, float* __restrict__ wT) {
  int idx = blockIdx.x * 256 + threadIdx.x;
  if (idx >= 64 * 64 * 15) return;
  int o = idx & 63, i = (idx >> 6) & 63, k = idx >> 12;
  wT[idx] = w[(o * 64 + i) * 15 + k];
}

// ---------------- pooled curvature/tangent streams -> (tp, b, c) ----------------
template <typename T>
__global__ __launch_bounds__(256) void k_pool_ct(const float* __restrict__ xb,
                                                 T* __restrict__ curvp,
                                                 T* __restrict__ tangp) {
  int row = blockIdx.x;  // b*64+c
  int b = row >> 6, c = row & 63;
  int tid = threadIdx.x;
  const float* s1 = xb + ((size_t)((b * 3 + 1) * 64 + c)) * TLEN + tid * 8;
  const float* s2 = xb + ((size_t)((b * 3 + 2) * 64 + c)) * TLEN + tid * 8;
  double p1 = 0.0, p2 = 0.0;
#pragma unroll
  for (int j = 0; j < 8; ++j) { p1 += (double)s1[j]; p2 += (double)s2[j]; }
  curvp[(size_t)tid * 2048 + row] = (T)(p1 * 0.125);
  tangp[(size_t)tid * 2048 + row] = (T)(p2 * 0.125);
}

// ---------------- enc (gaussian, f64) fused with conv1: 128 o x 128 t tile ----------
// AsT[kk][o] transposed weights -> vector LDS reads in inner loop; gaussian encode
// fused into the staging loader (no rxb buffer).
template <typename T>
__global__ __launch_bounds__(256, 2) void k_enc_conv1(const float* __restrict__ xb,
                                                      const float* __restrict__ w,
                                                      const float* __restrict__ mu,
                                                      const float* __restrict__ sigma,
                                                      T* __restrict__ h1) {
  __shared__ float AsT[32][132];    // [local i][o]
  __shared__ double Bs[32][132];    // [local i][t]
  __shared__ double smu[4], sinv[4];
  int b = blockIdx.x, t0 = blockIdx.y * 128, tid = threadIdx.x;
  if (tid < 4) {
    smu[tid] = (double)mu[tid];
    double s = (double)sigma[tid];
    sinv[tid] = 1.0 / (2.0 * s * s + 1e-6);
  }
  double acc[8][8] = {};
  int to = (tid >> 4) * 8, tt = (tid & 15) * 8;
  for (int kc = 0; kc < 24; ++kc) {
    int i0 = kc * 32;
    __syncthreads();   // guard reuse of AsT/Bs (also covers smu init on kc==0)
    // stage AsT: AsT[ii][o] = w[o][i0+ii]
    {
      int idx = tid * 4;             // 4096 floats per chunk
      int o = idx >> 5, ii = idx & 31;
      float4 v4 = *(const float4*)(w + (size_t)o * 768 + i0 + ii);
      AsT[ii][o] = v4.x; AsT[ii + 1][o] = v4.y; AsT[ii + 2][o] = v4.z; AsT[ii + 3][o] = v4.w;
      idx += 1024; o = idx >> 5; ii = idx & 31;
      v4 = *(const float4*)(w + (size_t)o * 768 + i0 + ii);
      AsT[ii][o] = v4.x; AsT[ii + 1][o] = v4.y; AsT[ii + 2][o] = v4.z; AsT[ii + 3][o] = v4.w;
      idx += 1024; o = idx >> 5; ii = idx & 31;
      v4 = *(const float4*)(w + (size_t)o * 768 + i0 + ii);
      AsT[ii][o] = v4.x; AsT[ii + 1][o] = v4.y; AsT[ii + 2][o] = v4.z; AsT[ii + 3][o] = v4.w;
      idx += 1024; o = idx >> 5; ii = idx & 31;
      v4 = *(const float4*)(w + (size_t)o * 768 + i0 + ii);
      AsT[ii][o] = v4.x; AsT[ii + 1][o] = v4.y; AsT[ii + 2][o] = v4.z; AsT[ii + 3][o] = v4.w;
    }
    // stage Bs with fused gaussian encode: chunk = 8 c-rows x 4 gaussians, f fixed
    {
      int f = i0 >> 8;
      int cb = (i0 >> 2) & 63;
      int c = tid >> 5, t4 = (tid & 31) * 4;
      float4 x4 = *(const float4*)(xb + ((size_t)((b * 3 + f) * 64 + cb + c)) * TLEN + t0 + t4);
      double xv[4] = {(double)x4.x, (double)x4.y, (double)x4.z, (double)x4.w};
#pragma unroll
      for (int g = 0; g < 4; ++g) {
        double m = smu[g], inv = sinv[g];
#pragma unroll
        for (int d = 0; d < 4; ++d) {
          double dd = xv[d] - m;
          Bs[c * 4 + g][t4 + d] = exp(-dd * dd * inv);
        }
      }
    }
    __syncthreads();
#pragma unroll
    for (int kk = 0; kk < 32; ++kk) {
      float4 a0 = *(const float4*)&AsT[kk][to];
      float4 a1 = *(const float4*)&AsT[kk][to + 4];
      double a[8] = {(double)a0.x, (double)a0.y, (double)a0.z, (double)a0.w,
                     (double)a1.x, (double)a1.y, (double)a1.z, (double)a1.w};
      double bb[8];
#pragma unroll
      for (int m = 0; m < 8; m += 2) {
        double2 p = *(const double2*)&Bs[kk][tt + m];
        bb[m] = p.x; bb[m + 1] = p.y;
      }
#pragma unroll
      for (int q = 0; q < 8; ++q)
#pragma unroll
        for (int j = 0; j < 8; ++j) acc[q][j] += a[q] * bb[j];
    }
  }
#pragma unroll
  for (int q = 0; q < 8; ++q) {
    T* op = h1 + ((size_t)(b * 128 + to + q)) * TLEN + t0 + tt;
#pragma unroll
    for (int j = 0; j < 8; ++j) op[j] = (T)acc[q][j];
  }
}

// ---------------- generic 1x1 conv: out[64][T] = W[64][K] * in[K][T], f64 math ------
template <int K, typename T>
__global__ __launch_bounds__(256) void k_conv1x1(const T* __restrict__ in,
                                                 const float* __restrict__ w,
                                                 T* __restrict__ out) {
  __shared__ float As[64][33];
  __shared__ double Bs[32][132];
  int b = blockIdx.x, t0 = blockIdx.y * 128, tid = threadIdx.x;
  double acc[4][8] = {};
  int to = (tid >> 4) * 4, tt = (tid & 15) * 8;
  for (int kc = 0; kc < K / 32; ++kc) {
    __syncthreads();
    for (int base = tid * 4; base < 2048; base += 1024) {
      int o = base >> 5, ii = base & 31;
      float4 v4 = *(const float4*)(w + (size_t)o * K + kc * 32 + ii);
      As[o][ii] = v4.x; As[o][ii + 1] = v4.y; As[o][ii + 2] = v4.z; As[o][ii + 3] = v4.w;
    }
    {
      int r = tid >> 3, cb = (tid & 7) * 16;
      const T* gp = in + ((size_t)(b * K + kc * 32 + r)) * TLEN + t0 + cb;
#pragma unroll
      for (int j = 0; j < 16; ++j) Bs[r][cb + j] = (double)gp[j];
    }
    __syncthreads();
#pragma unroll
    for (int kk = 0; kk < 32; ++kk) {
      double a0 = (double)As[to][kk], a1 = (double)As[to + 1][kk];
      double a2 = (double)As[to + 2][kk], a3 = (double)As[to + 3][kk];
      double bb[8];
#pragma unroll
      for (int j = 0; j < 8; ++j) bb[j] = Bs[kk][tt + j];
#pragma unroll
      for (int j = 0; j < 8; ++j) {
        acc[0][j] += a0 * bb[j];
        acc[1][j] += a1 * bb[j];
        acc[2][j] += a2 * bb[j];
        acc[3][j] += a3 * bb[j];
      }
    }
  }
#pragma unroll
  for (int q = 0; q < 4; ++q) {
    T* op = out + ((size_t)(b * 64 + to + q)) * TLEN + t0 + tt;
#pragma unroll
    for (int j = 0; j < 8; ++j) op[j] = (T)acc[q][j];
  }
}

// ---------------- temporal conv k=15 pad=7, f64, k-inner register blocking ----------
// Per i: 18 contiguous doubles -> registers (16B-aligned double2 reads, 2-way = free),
// weights per (i,k) as float4 from LDS chunk Ws[8][15][64]. 240 FMA per 24 LDS instrs.
template <typename T>
__global__ __launch_bounds__(256) void k_tconv1(const T* __restrict__ h2,
                                                const float* __restrict__ wT,
                                                T* __restrict__ h3) {
  __shared__ __align__(16) double In[64][80];   // x: 0..77 <-> t = t0-7 .. t0+70
  __shared__ float Ws[8][15][64];               // [ii][k][o]
  int b = blockIdx.x, t0 = blockIdx.y * 64, tid = threadIdx.x;
  for (int idx = tid; idx < 64 * 78; idx += 256) {
    int i = idx / 78, x = idx - i * 78;
    int tg = t0 - 7 + x;
    double v = 0.0;
    if (tg >= 0 && tg < TLEN) v = (double)h2[((size_t)(b * 64 + i)) * TLEN + tg];
    In[i][x] = v;
  }
  double acc[4][4] = {};
  int og = (tid >> 4) * 4, tt2 = (tid & 15) * 4;
  for (int ic = 0; ic < 8; ++ic) {
    __syncthreads();   // In visible (ic==0); Ws reuse guard (ic>0)
    for (int idx = tid; idx < 15 * 8 * 16; idx += 256) {   // 1920 float4 loads
      int k = idx >> 7;                // /128
      int r = idx & 127;
      int ii = r >> 4, o4 = (r & 15) * 4;
      float4 v = *(const float4*)(wT + ((size_t)(k * 64 + ic * 8 + ii)) * 64 + o4);
      *(float4*)&Ws[ii][k][o4] = v;
    }
    __syncthreads();
#pragma unroll
    for (int ii = 0; ii < 8; ++ii) {
      int i = ic * 8 + ii;
      double r[18];
#pragma unroll
      for (int m = 0; m < 18; m += 2) {
        double2 p = *(const double2*)&In[i][tt2 + m];
        r[m] = p.x; r[m + 1] = p.y;
      }
#pragma unroll
      for (int k = 0; k < 15; ++k) {
        float4 w4 = *(const float4*)&Ws[ii][k][og];
        double w0 = (double)w4.x, w1 = (double)w4.y, w2 = (double)w4.z, w3 = (double)w4.w;
#pragma unroll
        for (int j = 0; j < 4; ++j) {
          double x = r[j + k];
          acc[0][j] += w0 * x;
          acc[1][j] += w1 * x;
          acc[2][j] += w2 * x;
          acc[3][j] += w3 * x;
        }
      }
    }
  }
#pragma unroll
  for (int q = 0; q < 4; ++q) {
    T* op = h3 + ((size_t)(b * 64 + og + q)) * TLEN + t0 + tt2;
#pragma unroll
    for (int j = 0; j < 4; ++j) op[j] = (T)acc[q][j];
  }
}

// ---------------- instance norm + relu, in place, f64 stats -------------------------
template <typename T>
__global__ __launch_bounds__(256) void k_instnorm_relu(T* __restrict__ h,
                                                       const float* __restrict__ gw,
                                                       const float* __restrict__ gb,
                                                       int chmask) {
  __shared__ double sm[4];
  int row = blockIdx.x, tid = threadIdx.x;
  int ch = row & chmask;
  T* base = h + (size_t)row * TLEN + tid * 8;
  double v[8];
#pragma unroll
  for (int j = 0; j < 8; ++j) v[j] = (double)base[j];
  double s = 0.0;
#pragma unroll
  for (int j = 0; j < 8; ++j) s += v[j];
  double mean = block_reduce_sum_d(s, sm) * (1.0 / 2048.0);
  double sq = 0.0;
#pragma unroll
  for (int j = 0; j < 8; ++j) { double d = v[j] - mean; sq += d * d; }
  double var = block_reduce_sum_d(sq, sm) * (1.0 / 2048.0);
  double scale = (double)gw[ch] / sqrt(var + 1e-5);
  double shift = (double)gb[ch] - mean * scale;
#pragma unroll
  for (int j = 0; j < 8; ++j) base[j] = (T)fmax(v[j] * scale + shift, 0.0);
}

// ---------------- IN4 + relu + avgpool8 -> cbuf[tp][b][c], f64 ----------------------
template <typename T>
__global__ __launch_bounds__(256) void k_in4_pool(const T* __restrict__ h,
                                                  const float* __restrict__ gw,
                                                  const float* __restrict__ gb,
                                                  T* __restrict__ cbuf) {
  __shared__ double sm[4];
  int row = blockIdx.x, tid = threadIdx.x;
  int ch = row & 63;
  const T* base = h + (size_t)row * TLEN + tid * 8;
  double v[8];
#pragma unroll
  for (int j = 0; j < 8; ++j) v[j] = (double)base[j];
  double s = 0.0;
#pragma unroll
  for (int j = 0; j < 8; ++j) s += v[j];
  double mean = block_reduce_sum_d(s, sm) * (1.0 / 2048.0);
  double sq = 0.0;
#pragma unroll
  for (int j = 0; j < 8; ++j) { double d = v[j] - mean; sq += d * d; }
  double var = block_reduce_sum_d(sq, sm) * (1.0 / 2048.0);
  double scale = (double)gw[ch] / sqrt(var + 1e-5);
  double shift = (double)gb[ch] - mean * scale;
  double p = 0.0;
#pragma unroll
  for (int j = 0; j < 8; ++j) p += fmax(v[j] * scale + shift, 0.0);
  cbuf[(size_t)tid * 2048 + row] = (T)(p * 0.125);
}

// ---------------- GD-LIF scan + softmax attention readout, f64 ---------------------
template <typename T>
__global__ __launch_bounds__(64) void k_scan(const T* __restrict__ cbuf,
                                             const T* __restrict__ curvp,
                                             const T* __restrict__ tangp,
                                             const float* __restrict__ alpha,
                                             const float* __restrict__ gamma,
                                             const float* __restrict__ betal,
                                             double* __restrict__ ofeat) {
  int id = blockIdx.x * 64 + threadIdx.x;  // b*64+c
  double a = (double)alpha[0], g = (double)gamma[0], bl = (double)betal[0];
  double mmax = -1e300, ssum = 0.0;
  for (int tp = 0; tp < TP; ++tp) {
    double v = (double)curvp[(size_t)tp * 2048 + id];
    double nm = fmax(mmax, v);
    ssum = ssum * exp(mmax - nm) + exp(v - nm);
    mmax = nm;
  }
  double invs = 1.0 / ssum;
  double mem = 0.0, acc = 0.0;
  for (int tp = 0; tp < TP; ++tp) {
    double x = (double)cbuf[(size_t)tp * 2048 + id];
    double cu = (double)curvp[(size_t)tp * 2048 + id];
    double ta = (double)tangp[(size_t)tp * 2048 + id];
    double vth = 1.0 + a * ta;
    double beta = 1.0 / (1.0 + exp(g * cu - bl));
    mem = beta * mem + x;
    if (mem - vth > 0.0) {
      acc += exp(cu - mmax) * invs;
      mem -= vth;
    }
  }
  ofeat[id] = acc;
}

// ---------------- final fc: (32,64) @ (4,64)^T + b, f64 -----------------------------
__global__ void k_fc(const double* __restrict__ ofeat, const float* __restrict__ fw,
                     const float* __restrict__ fb, float* __restrict__ out) {
  int tid = threadIdx.x;
  if (tid >= 128) return;
  int b = tid >> 2, j = tid & 3;
  double s = (double)fb[j];
#pragma unroll
  for (int c = 0; c < 64; ++c) s += ofeat[b * 64 + c] * (double)fw[j * 64 + c];
  out[b * 4 + j] = (float)s;
}

// ---------------- host-side templated launcher --------------------------------------
template <typename T>
static void run_all(void* const* d_in, float* out, char* wsb, hipStream_t stream) {
  const float* xb    = (const float*)d_in[0];
  const float* mu    = (const float*)d_in[1];
  const float* sigma = (const float*)d_in[2];
  const float* w1    = (const float*)d_in[3];
  const float* in1w  = (const float*)d_in[4];
  const float* in1b  = (const float*)d_in[5];
  const float* w2    = (const float*)d_in[6];
  const float* in2w  = (const float*)d_in[7];
  const float* in2b  = (const float*)d_in[8];
  const float* wt1   = (const float*)d_in[9];
  const float* in3w  = (const float*)d_in[10];
  const float* in3b  = (const float*)d_in[11];
  const float* w4    = (const float*)d_in[12];
  const float* in4w  = (const float*)d_in[13];
  const float* in4b  = (const float*)d_in[14];
  const float* alpha = (const float*)d_in[15];
  const float* gamma = (const float*)d_in[16];
  const float* betal = (const float*)d_in[17];
  const float* fcw   = (const float*)d_in[18];
  const float* fcb   = (const float*)d_in[19];

  size_t sT = sizeof(T);
  T* h1 = (T*)wsb;                                   // 8,388,608 elems (alias h3)
  T* h2 = (T*)(wsb + (size_t)8388608 * sT);          // 4,194,304 elems (alias h4)
  T* h3 = h1;
  T* h4 = h2;
  float* wT = (float*)(wsb + (size_t)12582912 * sT); // 61,440 f32
  char* p = wsb + (size_t)12582912 * sT + 245760;
  T* curvp = (T*)p;
  T* tangp = (T*)(p + (size_t)524288 * sT);
  T* cbuf  = (T*)(p + (size_t)2 * 524288 * sT);
  double* ofeat = (double*)(p + (size_t)3 * 524288 * sT);

  k_repack_w<<<dim3(240), dim3(256), 0, stream>>>(wt1, wT);
  k_pool_ct<T><<<dim3(2048), dim3(256), 0, stream>>>(xb, curvp, tangp);
  k_enc_conv1<T><<<dim3(32, 16), dim3(256), 0, stream>>>(xb, w1, mu, sigma, h1);
  k_instnorm_relu<T><<<dim3(4096), dim3(256), 0, stream>>>(h1, in1w, in1b, 127);
  k_conv1x1<128, T><<<dim3(32, 16), dim3(256), 0, stream>>>(h1, w2, h2);
  k_instnorm_relu<T><<<dim3(2048), dim3(256), 0, stream>>>(h2, in2w, in2b, 63);
  k_tconv1<T><<<dim3(32, 32), dim3(256), 0, stream>>>(h2, wT, h3);
  k_instnorm_relu<T><<<dim3(2048), dim3(256), 0, stream>>>(h3, in3w, in3b, 63);
  k_conv1x1<64, T><<<dim3(32, 16), dim3(256), 0, stream>>>(h3, w4, h4);
  k_in4_pool<T><<<dim3(2048), dim3(256), 0, stream>>>(h4, in4w, in4b, cbuf);
  k_scan<T><<<dim3(32), dim3(64), 0, stream>>>(cbuf, curvp, tangp, alpha, gamma, betal, ofeat);
  k_fc<<<dim3(1), dim3(128), 0, stream>>>(ofeat, fcw, fcb, out);
}

extern "C" void kernel_launch(void* const* d_in, const int* in_sizes, int n_in,
                              void* d_out, int out_size, void* d_ws, size_t ws_size,
                              hipStream_t stream) {
  // f64-storage footprint: 12,582,912*8 + 245,760 + 3*524,288*8 + 16,384 = 113,508,352 B
  const size_t NEED64 = 113508352ull;
  if (ws_size >= NEED64)
    run_all<double>(d_in, (float*)d_out, (char*)d_ws, stream);
  else
    run_all<float>(d_in, (float*)d_out, (char*)d_ws, stream);
}

// Round 4
// 746.468 us; speedup vs baseline: 1.5813x; 1.1744x over previous
//
#include <hip/hip_runtime.h>
#include <math.h>

#define TLEN 2048
#define TP 256

// ---------------- helpers ----------------
__device__ __forceinline__ double block_reduce_sum_d(double v, double* sm) {
#pragma unroll
  for (int off = 32; off > 0; off >>= 1) v += __shfl_down(v, off, 64);
  int lane = threadIdx.x & 63, wid = threadIdx.x >> 6;
  __syncthreads();
  if (lane == 0) sm[wid] = v;
  __syncthreads();
  double r = sm[0] + sm[1] + sm[2] + sm[3];
  __syncthreads();
  return r;
}

// ---------------- repack tconv1 weights: w[o][i][k] -> wT[k][i][o] (f32, exact) ------
__global__ void k_repack_w(const float* __restrict__ w, float* __restrict__ wT) {
  int idx = blockIdx.x * 256 + threadIdx.x;
  if (idx >= 64 * 64 * 15) return;
  int o = idx & 63, i = (idx >> 6) & 63, k = idx >> 12;
  wT[idx] = w[(o * 64 + i) * 15 + k];
}

// ---------------- pooled streams -> row-major [row][tp] ----------------
template <typename T>
__global__ __launch_bounds__(256) void k_pool_ct(const float* __restrict__ xb,
                                                 T* __restrict__ curvp,
                                                 T* __restrict__ tangp) {
  int row = blockIdx.x;  // b*64+c
  int b = row >> 6, c = row & 63;
  int tid = threadIdx.x;
  const float* s1 = xb + ((size_t)((b * 3 + 1) * 64 + c)) * TLEN + tid * 8;
  const float* s2 = xb + ((size_t)((b * 3 + 2) * 64 + c)) * TLEN + tid * 8;
  double p1 = 0.0, p2 = 0.0;
#pragma unroll
  for (int j = 0; j < 8; ++j) { p1 += (double)s1[j]; p2 += (double)s2[j]; }
  curvp[(size_t)row * TP + tid] = (T)(p1 * 0.125);
  tangp[(size_t)row * TP + tid] = (T)(p2 * 0.125);
}

// ---------------- enc (gaussian, f64) fused with conv1: 128 o x 128 t tile ----------
// Interleaved t-mapping: lane l owns t = 2l + 32j (j=0..3), so all LDS traffic is
// 16 lanes x 16B contiguous (bank-conflict free) and stores stay 256B-contiguous.
template <typename T>
__global__ __launch_bounds__(256, 2) void k_enc_conv1(const float* __restrict__ xb,
                                                      const float* __restrict__ w,
                                                      const float* __restrict__ mu,
                                                      const float* __restrict__ sigma,
                                                      T* __restrict__ h1) {
  __shared__ float AsT[32][132];    // [local i][o]
  __shared__ double Bs[32][130];    // [local i][t] (pad to 130)
  __shared__ double smu[4], sinv[4];
  int b = blockIdx.x, t0 = blockIdx.y * 128, tid = threadIdx.x;
  if (tid < 4) {
    smu[tid] = (double)mu[tid];
    double s = (double)sigma[tid];
    sinv[tid] = 1.0 / (2.0 * s * s + 1e-6);
  }
  double acc[8][8] = {};
  int to = (tid >> 4) * 8, l = tid & 15;
  for (int kc = 0; kc < 24; ++kc) {
    int i0 = kc * 32;
    __syncthreads();   // guard reuse of AsT/Bs (also covers smu init on kc==0)
    // stage AsT: AsT[ii][o] = w[o][i0+ii]
    {
      int idx = tid * 4;             // 4096 floats per chunk
#pragma unroll
      for (int rep = 0; rep < 4; ++rep) {
        int o = idx >> 5, ii = idx & 31;
        float4 v4 = *(const float4*)(w + (size_t)o * 768 + i0 + ii);
        AsT[ii][o] = v4.x; AsT[ii + 1][o] = v4.y; AsT[ii + 2][o] = v4.z; AsT[ii + 3][o] = v4.w;
        idx += 1024;
      }
    }
    // stage Bs with fused gaussian encode (interleaved-friendly write pattern)
    {
      int f = i0 >> 8;
      int cb = (i0 >> 2) & 63;
      int c = tid >> 5, l2 = tid & 31;
#pragma unroll
      for (int h = 0; h < 2; ++h) {
        int t = 2 * l2 + 64 * h;
        float2 x2 = *(const float2*)(xb + ((size_t)((b * 3 + f) * 64 + cb + c)) * TLEN + t0 + t);
        double xv0 = (double)x2.x, xv1 = (double)x2.y;
#pragma unroll
        for (int g = 0; g < 4; ++g) {
          double m = smu[g], inv = sinv[g];
          double d0 = xv0 - m, d1 = xv1 - m;
          double2 e = {exp(-d0 * d0 * inv), exp(-d1 * d1 * inv)};
          *(double2*)&Bs[c * 4 + g][t] = e;
        }
      }
    }
    __syncthreads();
#pragma unroll
    for (int kk = 0; kk < 32; ++kk) {
      float4 a0 = *(const float4*)&AsT[kk][to];
      float4 a1 = *(const float4*)&AsT[kk][to + 4];
      double a[8] = {(double)a0.x, (double)a0.y, (double)a0.z, (double)a0.w,
                     (double)a1.x, (double)a1.y, (double)a1.z, (double)a1.w};
      double bb[8];
#pragma unroll
      for (int j = 0; j < 4; ++j) {
        double2 p = *(const double2*)&Bs[kk][2 * l + 32 * j];
        bb[2 * j] = p.x; bb[2 * j + 1] = p.y;
      }
#pragma unroll
      for (int q = 0; q < 8; ++q)
#pragma unroll
        for (int j = 0; j < 8; ++j) acc[q][j] += a[q] * bb[j];
    }
  }
#pragma unroll
  for (int q = 0; q < 8; ++q) {
    T* op = h1 + ((size_t)(b * 128 + to + q)) * TLEN + t0;
#pragma unroll
    for (int j = 0; j < 4; ++j) {
      op[2 * l + 32 * j]     = (T)acc[q][2 * j];
      op[2 * l + 32 * j + 1] = (T)acc[q][2 * j + 1];
    }
  }
}

// ---------------- generic 1x1 conv: out[64][T] = W[64][K] * in[K][T], f64 math ------
template <int K, typename T>
__global__ __launch_bounds__(256) void k_conv1x1(const T* __restrict__ in,
                                                 const float* __restrict__ w,
                                                 T* __restrict__ out) {
  __shared__ float As[64][33];
  __shared__ double Bs[32][130];
  int b = blockIdx.x, t0 = blockIdx.y * 128, tid = threadIdx.x;
  double acc[4][8] = {};
  int to = (tid >> 4) * 4, l = tid & 15;
  for (int kc = 0; kc < K / 32; ++kc) {
    __syncthreads();
    for (int base = tid * 4; base < 2048; base += 1024) {
      int o = base >> 5, ii = base & 31;
      float4 v4 = *(const float4*)(w + (size_t)o * K + kc * 32 + ii);
      As[o][ii] = v4.x; As[o][ii + 1] = v4.y; As[o][ii + 2] = v4.z; As[o][ii + 3] = v4.w;
    }
    {
      int r = tid >> 3, l8 = tid & 7;
      const T* gp = in + ((size_t)(b * K + kc * 32 + r)) * TLEN + t0;
#pragma unroll
      for (int q = 0; q < 8; ++q) {
        int t = 2 * l8 + 16 * q;
        double2 v = {(double)gp[t], (double)gp[t + 1]};
        *(double2*)&Bs[r][t] = v;
      }
    }
    __syncthreads();
#pragma unroll
    for (int kk = 0; kk < 32; ++kk) {
      double a0 = (double)As[to][kk], a1 = (double)As[to + 1][kk];
      double a2 = (double)As[to + 2][kk], a3 = (double)As[to + 3][kk];
      double bb[8];
#pragma unroll
      for (int j = 0; j < 4; ++j) {
        double2 p = *(const double2*)&Bs[kk][2 * l + 32 * j];
        bb[2 * j] = p.x; bb[2 * j + 1] = p.y;
      }
#pragma unroll
      for (int j = 0; j < 8; ++j) {
        acc[0][j] += a0 * bb[j];
        acc[1][j] += a1 * bb[j];
        acc[2][j] += a2 * bb[j];
        acc[3][j] += a3 * bb[j];
      }
    }
  }
#pragma unroll
  for (int q = 0; q < 4; ++q) {
    T* op = out + ((size_t)(b * 64 + to + q)) * TLEN + t0;
#pragma unroll
    for (int j = 0; j < 4; ++j) {
      op[2 * l + 32 * j]     = (T)acc[q][2 * j];
      op[2 * l + 32 * j + 1] = (T)acc[q][2 * j + 1];
    }
  }
}

// ---------------- temporal conv k=15 pad=7, f64, k-inner register blocking ----------
template <typename T>
__global__ __launch_bounds__(256) void k_tconv1(const T* __restrict__ h2,
                                                const float* __restrict__ wT,
                                                T* __restrict__ h3) {
  __shared__ __align__(16) double In[64][80];   // x: 0..77 <-> t = t0-7 .. t0+70
  __shared__ float Ws[8][15][64];               // [ii][k][o]
  int b = blockIdx.x, t0 = blockIdx.y * 64, tid = threadIdx.x;
  for (int idx = tid; idx < 64 * 78; idx += 256) {
    int i = idx / 78, x = idx - i * 78;
    int tg = t0 - 7 + x;
    double v = 0.0;
    if (tg >= 0 && tg < TLEN) v = (double)h2[((size_t)(b * 64 + i)) * TLEN + tg];
    In[i][x] = v;
  }
  double acc[4][4] = {};
  int og = (tid >> 4) * 4, tt2 = (tid & 15) * 4;
  for (int ic = 0; ic < 8; ++ic) {
    __syncthreads();   // In visible (ic==0); Ws reuse guard (ic>0)
    for (int idx = tid; idx < 15 * 8 * 16; idx += 256) {   // 1920 float4 loads
      int k = idx >> 7;
      int r = idx & 127;
      int ii = r >> 4, o4 = (r & 15) * 4;
      float4 v = *(const float4*)(wT + ((size_t)(k * 64 + ic * 8 + ii)) * 64 + o4);
      *(float4*)&Ws[ii][k][o4] = v;
    }
    __syncthreads();
#pragma unroll
    for (int ii = 0; ii < 8; ++ii) {
      int i = ic * 8 + ii;
      double r[18];
#pragma unroll
      for (int m = 0; m < 18; m += 2) {
        double2 p = *(const double2*)&In[i][tt2 + m];
        r[m] = p.x; r[m + 1] = p.y;
      }
#pragma unroll
      for (int k = 0; k < 15; ++k) {
        float4 w4 = *(const float4*)&Ws[ii][k][og];
        double w0 = (double)w4.x, w1 = (double)w4.y, w2 = (double)w4.z, w3 = (double)w4.w;
#pragma unroll
        for (int j = 0; j < 4; ++j) {
          double x = r[j + k];
          acc[0][j] += w0 * x;
          acc[1][j] += w1 * x;
          acc[2][j] += w2 * x;
          acc[3][j] += w3 * x;
        }
      }
    }
  }
#pragma unroll
  for (int q = 0; q < 4; ++q) {
    T* op = h3 + ((size_t)(b * 64 + og + q)) * TLEN + t0 + tt2;
#pragma unroll
    for (int j = 0; j < 4; ++j) op[j] = (T)acc[q][j];
  }
}

// ---------------- instance norm + relu, in place, f64 stats -------------------------
template <typename T>
__global__ __launch_bounds__(256) void k_instnorm_relu(T* __restrict__ h,
                                                       const float* __restrict__ gw,
                                                       const float* __restrict__ gb,
                                                       int chmask) {
  __shared__ double sm[4];
  int row = blockIdx.x, tid = threadIdx.x;
  int ch = row & chmask;
  T* base = h + (size_t)row * TLEN + tid * 8;
  double v[8];
#pragma unroll
  for (int j = 0; j < 8; ++j) v[j] = (double)base[j];
  double s = 0.0;
#pragma unroll
  for (int j = 0; j < 8; ++j) s += v[j];
  double mean = block_reduce_sum_d(s, sm) * (1.0 / 2048.0);
  double sq = 0.0;
#pragma unroll
  for (int j = 0; j < 8; ++j) { double d = v[j] - mean; sq += d * d; }
  double var = block_reduce_sum_d(sq, sm) * (1.0 / 2048.0);
  double scale = (double)gw[ch] / sqrt(var + 1e-5);
  double shift = (double)gb[ch] - mean * scale;
#pragma unroll
  for (int j = 0; j < 8; ++j) base[j] = (T)fmax(v[j] * scale + shift, 0.0);
}

// ---------------- IN4 + relu + avgpool8 -> cbuf[row][tp], f64 -----------------------
template <typename T>
__global__ __launch_bounds__(256) void k_in4_pool(const T* __restrict__ h,
                                                  const float* __restrict__ gw,
                                                  const float* __restrict__ gb,
                                                  T* __restrict__ cbuf) {
  __shared__ double sm[4];
  int row = blockIdx.x, tid = threadIdx.x;
  int ch = row & 63;
  const T* base = h + (size_t)row * TLEN + tid * 8;
  double v[8];
#pragma unroll
  for (int j = 0; j < 8; ++j) v[j] = (double)base[j];
  double s = 0.0;
#pragma unroll
  for (int j = 0; j < 8; ++j) s += v[j];
  double mean = block_reduce_sum_d(s, sm) * (1.0 / 2048.0);
  double sq = 0.0;
#pragma unroll
  for (int j = 0; j < 8; ++j) { double d = v[j] - mean; sq += d * d; }
  double var = block_reduce_sum_d(sq, sm) * (1.0 / 2048.0);
  double scale = (double)gw[ch] / sqrt(var + 1e-5);
  double shift = (double)gb[ch] - mean * scale;
  double p = 0.0;
#pragma unroll
  for (int j = 0; j < 8; ++j) p += fmax(v[j] * scale + shift, 0.0);
  cbuf[(size_t)row * TP + tid] = (T)(p * 0.125);
}

// ---------------- GD-LIF scan + softmax attention readout, f64 ---------------------
// row-major inputs: [id][tp]
template <typename T>
__global__ __launch_bounds__(64) void k_scan(const T* __restrict__ cbuf,
                                             const T* __restrict__ curvp,
                                             const T* __restrict__ tangp,
                                             const float* __restrict__ alpha,
                                             const float* __restrict__ gamma,
                                             const float* __restrict__ betal,
                                             double* __restrict__ ofeat) {
  int id = blockIdx.x * 64 + threadIdx.x;  // b*64+c
  double a = (double)alpha[0], g = (double)gamma[0], bl = (double)betal[0];
  const T* cu_p = curvp + (size_t)id * TP;
  const T* ta_p = tangp + (size_t)id * TP;
  const T* cb_p = cbuf + (size_t)id * TP;
  double mmax = -1e300, ssum = 0.0;
  for (int tp = 0; tp < TP; ++tp) {
    double v = (double)cu_p[tp];
    double nm = fmax(mmax, v);
    ssum = ssum * exp(mmax - nm) + exp(v - nm);
    mmax = nm;
  }
  double invs = 1.0 / ssum;
  double mem = 0.0, acc = 0.0;
  for (int tp = 0; tp < TP; ++tp) {
    double x = (double)cb_p[tp];
    double cu = (double)cu_p[tp];
    double ta = (double)ta_p[tp];
    double vth = 1.0 + a * ta;
    double beta = 1.0 / (1.0 + exp(g * cu - bl));
    mem = beta * mem + x;
    if (mem - vth > 0.0) {
      acc += exp(cu - mmax) * invs;
      mem -= vth;
    }
  }
  ofeat[id] = acc;
}

// ---------------- final fc: (32,64) @ (4,64)^T + b, f64 -----------------------------
__global__ void k_fc(const double* __restrict__ ofeat, const float* __restrict__ fw,
                     const float* __restrict__ fb, float* __restrict__ out) {
  int tid = threadIdx.x;
  if (tid >= 128) return;
  int b = tid >> 2, j = tid & 3;
  double s = (double)fb[j];
#pragma unroll
  for (int c = 0; c < 64; ++c) s += ofeat[b * 64 + c] * (double)fw[j * 64 + c];
  out[b * 4 + j] = (float)s;
}

// ---------------- host-side templated launcher --------------------------------------
template <typename T>
static void run_all(void* const* d_in, float* out, char* wsb, hipStream_t stream) {
  const float* xb    = (const float*)d_in[0];
  const float* mu    = (const float*)d_in[1];
  const float* sigma = (const float*)d_in[2];
  const float* w1    = (const float*)d_in[3];
  const float* in1w  = (const float*)d_in[4];
  const float* in1b  = (const float*)d_in[5];
  const float* w2    = (const float*)d_in[6];
  const float* in2w  = (const float*)d_in[7];
  const float* in2b  = (const float*)d_in[8];
  const float* wt1   = (const float*)d_in[9];
  const float* in3w  = (const float*)d_in[10];
  const float* in3b  = (const float*)d_in[11];
  const float* w4    = (const float*)d_in[12];
  const float* in4w  = (const float*)d_in[13];
  const float* in4b  = (const float*)d_in[14];
  const float* alpha = (const float*)d_in[15];
  const float* gamma = (const float*)d_in[16];
  const float* betal = (const float*)d_in[17];
  const float* fcw   = (const float*)d_in[18];
  const float* fcb   = (const float*)d_in[19];

  size_t sT = sizeof(T);
  T* h1 = (T*)wsb;                                   // 8,388,608 elems (alias h3)
  T* h2 = (T*)(wsb + (size_t)8388608 * sT);          // 4,194,304 elems (alias h4)
  T* h3 = h1;
  T* h4 = h2;
  float* wT = (float*)(wsb + (size_t)12582912 * sT); // 61,440 f32
  char* p = wsb + (size_t)12582912 * sT + 245760;
  T* curvp = (T*)p;
  T* tangp = (T*)(p + (size_t)524288 * sT);
  T* cbuf  = (T*)(p + (size_t)2 * 524288 * sT);
  double* ofeat = (double*)(p + (size_t)3 * 524288 * sT);

  k_repack_w<<<dim3(240), dim3(256), 0, stream>>>(wt1, wT);
  k_pool_ct<T><<<dim3(2048), dim3(256), 0, stream>>>(xb, curvp, tangp);
  k_enc_conv1<T><<<dim3(32, 16), dim3(256), 0, stream>>>(xb, w1, mu, sigma, h1);
  k_instnorm_relu<T><<<dim3(4096), dim3(256), 0, stream>>>(h1, in1w, in1b, 127);
  k_conv1x1<128, T><<<dim3(32, 16), dim3(256), 0, stream>>>(h1, w2, h2);
  k_instnorm_relu<T><<<dim3(2048), dim3(256), 0, stream>>>(h2, in2w, in2b, 63);
  k_tconv1<T><<<dim3(32, 32), dim3(256), 0, stream>>>(h2, wT, h3);
  k_instnorm_relu<T><<<dim3(2048), dim3(256), 0, stream>>>(h3, in3w, in3b, 63);
  k_conv1x1<64, T><<<dim3(32, 16), dim3(256), 0, stream>>>(h3, w4, h4);
  k_in4_pool<T><<<dim3(2048), dim3(256), 0, stream>>>(h4, in4w, in4b, cbuf);
  k_scan<T><<<dim3(32), dim3(64), 0, stream>>>(cbuf, curvp, tangp, alpha, gamma, betal, ofeat);
  k_fc<<<dim3(1), dim3(128), 0, stream>>>(ofeat, fcw, fcb, out);
}

extern "C" void kernel_launch(void* const* d_in, const int* in_sizes, int n_in,
                              void* d_out, int out_size, void* d_ws, size_t ws_size,
                              hipStream_t stream) {
  // f64-storage footprint: 12,582,912*8 + 245,760 + 3*524,288*8 + 16,384 = 113,508,352 B
  const size_t NEED64 = 113508352ull;
  if (ws_size >= NEED64)
    run_all<double>(d_in, (float*)d_out, (char*)d_ws, stream);
  else
    run_all<float>(d_in, (float*)d_out, (char*)d_ws, stream);
}